// Round 1
// baseline (392.920 us; speedup 1.0000x reference)
//
#include <hip/hip_runtime.h>
#include <hip/hip_bf16.h>

#define M_DIM 8192
#define N_DIM 4096
#define K_DIM 4096

using bf16x8 = __attribute__((ext_vector_type(8))) short;
using f32x4  = __attribute__((ext_vector_type(4))) float;

// ---------- fp32 -> bf16 (RNE via bit math; no NaNs in this data) ----------
__device__ __forceinline__ unsigned short f2bf(float f) {
    unsigned int u = __float_as_uint(f);
    unsigned int r = u + 0x7fffu + ((u >> 16) & 1u);
    return (unsigned short)(r >> 16);
}

__global__ void cvt_f32_to_bf16(const float* __restrict__ src,
                                unsigned short* __restrict__ dst, int n4) {
    int i = blockIdx.x * blockDim.x + threadIdx.x;
    const int stride = gridDim.x * blockDim.x;
    const float4* s4 = reinterpret_cast<const float4*>(src);
    uint2* d2 = reinterpret_cast<uint2*>(dst);
    for (; i < n4; i += stride) {
        float4 v = s4[i];
        uint2 o;
        o.x = (unsigned)f2bf(v.x) | ((unsigned)f2bf(v.y) << 16);
        o.y = (unsigned)f2bf(v.z) | ((unsigned)f2bf(v.w) << 16);
        d2[i] = o;
    }
}

// ---------- async global->LDS, 16B per lane ----------
__device__ __forceinline__ void gload16(const unsigned short* g, void* l) {
    __builtin_amdgcn_global_load_lds(
        (const __attribute__((address_space(1))) void*)g,
        (__attribute__((address_space(3))) void*)l, 16, 0, 0);
}

// ---------- bf16 MFMA GEMM: out[M,N] = Xb[M,K] * Wb[N,K]^T + bias ----------
// 128x128 tile, BK=64, 4 waves (2x2 quadrants of 64x64), single-buffered LDS,
// T2 XOR swizzle (byte ^= (row&7)<<4) applied as pre-swizzled global source
// (linear LDS dest for global_load_lds) + swizzled ds_read.
__global__ __launch_bounds__(256) void gemm_bf16_mfma(
        const unsigned short* __restrict__ xb,   // [M,K] bf16 bits
        const unsigned short* __restrict__ wb,   // [N,K] bf16 bits
        const float* __restrict__ bias,          // [N]
        float* __restrict__ out) {               // [M,N]
    __shared__ unsigned short sA[128 * 64];
    __shared__ unsigned short sB[128 * 64];

    // XCD-aware bijective swizzle: grid = 2048, 2048 % 8 == 0
    const int nwg = (M_DIM / 128) * (N_DIM / 128);   // 2048
    const int q = nwg / 8;                            // 256
    int bid = blockIdx.x;
    int bid2 = (bid & 7) * q + (bid >> 3);
    const int tm = bid2 & 63;       // 64 M-tiles
    const int tn = bid2 >> 6;       // 32 N-tiles
    const int r0 = tm * 128;
    const int c0 = tn * 128;

    const int tid  = threadIdx.x;
    const int lane = tid & 63;
    const int wave = tid >> 6;
    const int wr = wave >> 1;       // 0..1  (64-row half)
    const int wc = wave & 1;        // 0..1  (64-col half)
    const int lr = lane & 15;       // fragment row/col
    const int t  = lane >> 4;       // 0..3  (k sub-slot)

    // --- ds_read offsets (shorts), swizzled ---
    int aoff[2][4], boff[2][4];
#pragma unroll
    for (int m = 0; m < 4; ++m) {
        int rowA = wr * 64 + m * 16 + lr;
        int swA  = (rowA & 7) << 4;
        int rowB = wc * 64 + m * 16 + lr;
        int swB  = (rowB & 7) << 4;
#pragma unroll
        for (int kk = 0; kk < 2; ++kk) {
            int cb = kk * 64 + t * 16;            // byte col within 128B row
            aoff[kk][m] = rowA * 64 + ((cb ^ swA) >> 1);
            boff[kk][m] = rowB * 64 + ((cb ^ swB) >> 1);
        }
    }

    // --- staging addresses: linear LDS dest, inverse-swizzled global src ---
    const int sRow   = lane >> 3;                       // 0..7
    const int sChunk = (lane & 7) ^ sRow;               // inverse swizzle
    int aSrc[4], bSrc[4];
    char* ldsA[4];
    char* ldsB[4];
#pragma unroll
    for (int r = 0; r < 4; ++r) {
        int row = r * 32 + wave * 8 + sRow;             // 0..127 within tile
        aSrc[r] = (r0 + row) * K_DIM + sChunk * 8;
        bSrc[r] = (c0 + row) * K_DIM + sChunk * 8;
        ldsA[r] = (char*)sA + (r * 4 + wave) * 1024;    // wave-uniform base
        ldsB[r] = (char*)sB + (r * 4 + wave) * 1024;
    }

    f32x4 acc[4][4];
#pragma unroll
    for (int m = 0; m < 4; ++m)
#pragma unroll
        for (int n = 0; n < 4; ++n)
            acc[m][n] = (f32x4){0.f, 0.f, 0.f, 0.f};

    for (int kt = 0; kt < K_DIM / 64; ++kt) {
        const int ko = kt * 64;
#pragma unroll
        for (int r = 0; r < 4; ++r) {
            gload16(xb + aSrc[r] + ko, ldsA[r]);
            gload16(wb + bSrc[r] + ko, ldsB[r]);
        }
        __syncthreads();   // drains vmcnt(0): staged data visible
#pragma unroll
        for (int kk = 0; kk < 2; ++kk) {
            bf16x8 av[4], bv[4];
#pragma unroll
            for (int m = 0; m < 4; ++m)
                av[m] = *reinterpret_cast<const bf16x8*>(sA + aoff[kk][m]);
#pragma unroll
            for (int n = 0; n < 4; ++n)
                bv[n] = *reinterpret_cast<const bf16x8*>(sB + boff[kk][n]);
#pragma unroll
            for (int m = 0; m < 4; ++m)
#pragma unroll
                for (int n = 0; n < 4; ++n)
                    acc[m][n] = __builtin_amdgcn_mfma_f32_16x16x32_bf16(
                        av[m], bv[n], acc[m][n], 0, 0, 0);
        }
        __syncthreads();   // protect LDS before next stage
    }

    // --- epilogue: C/D layout col=lane&15, row=(lane>>4)*4+j ---
#pragma unroll
    for (int n = 0; n < 4; ++n) {
        const int col = c0 + wc * 64 + n * 16 + lr;
        const float bv = bias[col];
#pragma unroll
        for (int m = 0; m < 4; ++m) {
            const int row0 = r0 + wr * 64 + m * 16 + t * 4;
#pragma unroll
            for (int j = 0; j < 4; ++j)
                out[(row0 + j) * N_DIM + col] = acc[m][n][j] + bv;
        }
    }
}

// ---------- fp32 fallback (only if ws too small) ----------
__global__ void fallback_gemm_f32(const float* __restrict__ x,
                                  const float* __restrict__ w,
                                  const float* __restrict__ bias,
                                  float* __restrict__ out) {
    __shared__ float sX[2][4096];
    const int tid = threadIdx.x;
    const int col = blockIdx.x * 256 + tid;
    const int row0 = blockIdx.y * 2;
    for (int i = tid * 4; i < 8192; i += 1024) {
        int r = i >> 12, c = i & 4095;
        *(float4*)&sX[r][c] = *(const float4*)&x[(size_t)(row0 + r) * 4096 + c];
    }
    __syncthreads();
    const float4* wrow = (const float4*)&w[(size_t)col * 4096];
    float a0 = 0.f, a1 = 0.f;
    for (int k4 = 0; k4 < 1024; ++k4) {
        float4 wv = wrow[k4];
        int k = k4 << 2;
        a0 += wv.x * sX[0][k] + wv.y * sX[0][k + 1] + wv.z * sX[0][k + 2] + wv.w * sX[0][k + 3];
        a1 += wv.x * sX[1][k] + wv.y * sX[1][k + 1] + wv.z * sX[1][k + 2] + wv.w * sX[1][k + 3];
    }
    float bv = bias[col];
    out[(size_t)row0 * 4096 + col] = a0 + bv;
    out[(size_t)(row0 + 1) * 4096 + col] = a1 + bv;
}

extern "C" void kernel_launch(void* const* d_in, const int* in_sizes, int n_in,
                              void* d_out, int out_size, void* d_ws, size_t ws_size,
                              hipStream_t stream) {
    const float* x    = (const float*)d_in[0];   // [8192, 4096] f32
    const float* w    = (const float*)d_in[1];   // [4096, 4096] f32 (pre-masked)
    const float* bias = (const float*)d_in[2];   // [4096] f32
    float* out = (float*)d_out;                  // [8192, 4096] f32

    const size_t nX = (size_t)M_DIM * K_DIM;     // 33.5M
    const size_t nW = (size_t)N_DIM * K_DIM;     // 16.8M
    const size_t need = (nX + nW) * sizeof(unsigned short);  // 96 MiB

    if (ws_size >= need) {
        unsigned short* xb = (unsigned short*)d_ws;
        unsigned short* wb = xb + nX;
        cvt_f32_to_bf16<<<2048, 256, 0, stream>>>(x, xb, (int)(nX / 4));
        cvt_f32_to_bf16<<<1024, 256, 0, stream>>>(w, wb, (int)(nW / 4));
        gemm_bf16_mfma<<<(M_DIM / 128) * (N_DIM / 128), 256, 0, stream>>>(xb, wb, bias, out);
    } else {
        fallback_gemm_f32<<<dim3(N_DIM / 256, M_DIM / 2), 256, 0, stream>>>(x, w, bias, out);
    }
}

// Round 3
// 268.587 us; speedup vs baseline: 1.4629x; 1.4629x over previous
//
#include <hip/hip_runtime.h>
#include <hip/hip_bf16.h>

#define M_DIM 8192
#define N_DIM 4096
#define K_DIM 4096

using bf16x8 = __attribute__((ext_vector_type(8))) short;
using f32x4  = __attribute__((ext_vector_type(4))) float;

// ---------- fp32 -> bf16 (RNE via bit math) ----------
__device__ __forceinline__ unsigned short f2bf(float f) {
    unsigned int u = __float_as_uint(f);
    unsigned int r = u + 0x7fffu + ((u >> 16) & 1u);
    return (unsigned short)(r >> 16);
}

__global__ void cvt_f32_to_bf16(const float* __restrict__ src,
                                unsigned short* __restrict__ dst, int n4) {
    int i = blockIdx.x * blockDim.x + threadIdx.x;
    const int stride = gridDim.x * blockDim.x;
    const float4* s4 = reinterpret_cast<const float4*>(src);
    uint2* d2 = reinterpret_cast<uint2*>(dst);
    for (; i < n4; i += stride) {
        float4 v = s4[i];
        uint2 o;
        o.x = (unsigned)f2bf(v.x) | ((unsigned)f2bf(v.y) << 16);
        o.y = (unsigned)f2bf(v.z) | ((unsigned)f2bf(v.w) << 16);
        d2[i] = o;
    }
}

// ---------- async global->LDS, 16B per lane ----------
__device__ __forceinline__ void gload16(const unsigned short* g, char* l) {
    __builtin_amdgcn_global_load_lds(
        (const __attribute__((address_space(1))) void*)g,
        (__attribute__((address_space(3))) void*)l, 16, 0, 0);
}

// ============================================================================
// 256x256 8-phase bf16 MFMA GEMM (T1+T2+T3+T4+T5).
// 8 waves (2M x 4N), BK=64, dbuf 128KiB LDS.
// LDS regions per buffer: A = [q][128 rows][128B] where region-row rr maps to
//   global row r0 + (rr>>6)*128 + q*64 + (rr&63)          (16KB each, q in 0..1)
// B = [p][128 rows][128B], region-row rr -> global col
//   c0 + (rr>>5)*64 + p*32 + (rr&31)                       (p in 0..1)
// Per K-tile t: 4 phases, quadrants (q,p) = (0,0),(0,1),(1,1),(1,0);
// tile t stages tile t+1's regions in order [B-p0, A-q0, B-p1, A-q1].
// vmcnt(4) at ends of ph1, ph2, ph4. Steady-state ledger (per wave):
//   enter tile t: outstanding = {B-p1(t)x2, A-q1(t)x2}
//   ph1 +B-p0(t+1) -> 6, wait 4 -> B-p1(t) landed  (read in ph2)
//   ph2 +A-q0(t+1) -> 6, wait 4 -> A-q1(t) landed  (read in ph3)
//   ph3 +B-p1(t+1) -> 6, no wait
//   ph4 +A-q1(t+1) -> 8, wait 4 -> B-p0(t+1), A-q0(t+1) landed (read next ph1)
// LAST TILE: stage ktNext=(t+1)&(NT-1) (dummy re-stage of tile 0 into the dead
// buffer) so the ledger stays exact -- fixes the round-2 race where vmcnt(4)
// was a no-op and ph2/ph3 read un-landed data.
// T2 swizzle: LDS linear dest, inverse-swizzled global src, XOR'd ds_read.
// ============================================================================
__global__ __launch_bounds__(512, 2) void gemm_bf16_256_8ph(
        const unsigned short* __restrict__ xb,   // [M,K] bf16 bits
        const unsigned short* __restrict__ wb,   // [N,K] bf16 bits
        const float* __restrict__ bias,          // [N]
        float* __restrict__ out) {               // [M,N]
    extern __shared__ char lds[];
    char* ldsA = lds;           // [2 buf][2 q][16384 B]
    char* ldsB = lds + 65536;   // [2 buf][2 p][16384 B]

    // T1: XCD-bijective swizzle (nwg=512, 512%8==0)
    int bid = blockIdx.x;
    int bid2 = (bid & 7) * 64 + (bid >> 3);
    const int tm = bid2 & 31;         // 32 M-tiles
    const int tn = bid2 >> 5;         // 16 N-tiles
    const int r0 = tm * 256;
    const int c0 = tn * 256;

    const int tid  = threadIdx.x;
    const int lane = tid & 63;
    const int wave = tid >> 6;        // 0..7
    const int wm = wave >> 2;         // 0..1  (128-row half)
    const int wn = wave & 3;          // 0..3  (64-col strip)
    const int lr = lane & 15;
    const int t4 = lane >> 4;

    // --- ds_read offsets (bytes within one 16KB region), T2-swizzled ---
    int aRd[4][2], bRd[2][2];
    const int swz = (lr & 7) << 4;
#pragma unroll
    for (int ks = 0; ks < 2; ++ks) {
        const int cb = (ks * 64 + t4 * 16) ^ swz;
#pragma unroll
        for (int m = 0; m < 4; ++m)
            aRd[m][ks] = (wm * 64 + m * 16 + lr) * 128 + cb;
#pragma unroll
        for (int n = 0; n < 2; ++n)
            bRd[n][ks] = (wn * 32 + n * 16 + lr) * 128 + cb;
    }

    // --- staging: wave-uniform LDS dest (HW adds lane*16), inverse-swizzled
    //     global source ---
    const int rowInBlk = lane >> 3;                       // 0..7
    const int sChunk   = ((lane & 7) ^ rowInBlk) * 8;     // element offset
    int aSrcB[2], bSrcB[2], dstOff[2];
#pragma unroll
    for (int l = 0; l < 2; ++l) {
        const int R0 = wave * 16 + l * 8;                 // lds row base 0..120
        aSrcB[l] = (r0 + (R0 >> 6) * 128 + (R0 & 63) + rowInBlk) * K_DIM + sChunk;
        bSrcB[l] = (c0 + (R0 >> 5) * 64  + (R0 & 31) + rowInBlk) * K_DIM + sChunk;
        dstOff[l] = R0 * 128;                             // wave-uniform
    }

    auto STAGE_A = [&](int q, int kt, int nb) {
#pragma unroll
        for (int l = 0; l < 2; ++l)
            gload16(xb + aSrcB[l] + q * 64 * K_DIM + kt * 64,
                    ldsA + nb * 32768 + q * 16384 + dstOff[l]);
    };
    auto STAGE_B = [&](int p, int kt, int nb) {
#pragma unroll
        for (int l = 0; l < 2; ++l)
            gload16(wb + bSrcB[l] + p * 32 * K_DIM + kt * 64,
                    ldsB + nb * 32768 + p * 16384 + dstOff[l]);
    };

    f32x4 acc[8][4];
#pragma unroll
    for (int i = 0; i < 8; ++i)
#pragma unroll
        for (int j = 0; j < 4; ++j)
            acc[i][j] = (f32x4){0.f, 0.f, 0.f, 0.f};

    bf16x8 av[4][2], bv0[2][2], bv1[2][2];

#define MFMA_QUAD(M0, N0, BV)                                                  \
    do {                                                                       \
        __builtin_amdgcn_s_setprio(1);                                         \
        _Pragma("unroll") for (int m = 0; m < 4; ++m)                          \
        _Pragma("unroll") for (int n = 0; n < 2; ++n)                          \
        _Pragma("unroll") for (int ks = 0; ks < 2; ++ks)                       \
            acc[(M0) + m][(N0) + n] = __builtin_amdgcn_mfma_f32_16x16x32_bf16( \
                av[m][ks], BV[n][ks], acc[(M0) + m][(N0) + n], 0, 0, 0);       \
        __builtin_amdgcn_s_setprio(0);                                         \
    } while (0)

#define LOAD_A(Q, BUF)                                                         \
    _Pragma("unroll") for (int m = 0; m < 4; ++m)                              \
    _Pragma("unroll") for (int ks = 0; ks < 2; ++ks)                           \
        av[m][ks] = *(const bf16x8*)(ldsA + (BUF) * 32768 + (Q) * 16384 + aRd[m][ks]);

#define LOAD_B(P, BUF, BV)                                                     \
    _Pragma("unroll") for (int n = 0; n < 2; ++n)                              \
    _Pragma("unroll") for (int ks = 0; ks < 2; ++ks)                           \
        BV[n][ks] = *(const bf16x8*)(ldsB + (BUF) * 32768 + (P) * 16384 + bRd[n][ks]);

    // --- prologue: stage tile 0 in steady-state order ---
    STAGE_B(0, 0, 0);
    STAGE_A(0, 0, 0);
    STAGE_B(1, 0, 0);
    STAGE_A(1, 0, 0);
    asm volatile("s_waitcnt vmcnt(4)\n\ts_barrier" ::: "memory");

    const int NT = K_DIM / 64;   // 64
    for (int t = 0; t < NT; ++t) {
        const int buf = t & 1, nbuf = buf ^ 1;
        const int ktNext = (t + 1) & (NT - 1);   // last tile: dummy re-stage of 0
        // ---- ph1: quadrant (0,0); stage B-p0(next) ----
        LOAD_A(0, buf);
        LOAD_B(0, buf, bv0);
        STAGE_B(0, ktNext, nbuf);
        MFMA_QUAD(0, 0, bv0);
        asm volatile("s_waitcnt vmcnt(4)\n\ts_barrier" ::: "memory");
        // ---- ph2: quadrant (0,1); stage A-q0(next) ----
        LOAD_B(1, buf, bv1);
        STAGE_A(0, ktNext, nbuf);
        MFMA_QUAD(0, 2, bv1);
        asm volatile("s_waitcnt vmcnt(4)\n\ts_barrier" ::: "memory");
        // ---- ph3: quadrant (1,1); stage B-p1(next) ----
        LOAD_A(1, buf);
        STAGE_B(1, ktNext, nbuf);
        MFMA_QUAD(4, 2, bv1);
        asm volatile("s_barrier" ::: "memory");
        // ---- ph4: quadrant (1,0); stage A-q1(next) ----
        STAGE_A(1, ktNext, nbuf);
        MFMA_QUAD(4, 0, bv0);
        asm volatile("s_waitcnt vmcnt(4)\n\ts_barrier" ::: "memory");
    }
    asm volatile("s_waitcnt vmcnt(0)" ::: "memory");   // drain dummy stages

    // --- epilogue: C/D layout col=lane&15, row=t4*4+j ---
#pragma unroll
    for (int ni = 0; ni < 4; ++ni) {
        const int col = c0 + wn * 64 + (ni >> 1) * 32 + (ni & 1) * 16 + lr;
        const float bvs = bias[col];
#pragma unroll
        for (int mi = 0; mi < 8; ++mi) {
            const int row0 = r0 + wm * 128 + (mi >> 2) * 64 + (mi & 3) * 16 + t4 * 4;
#pragma unroll
            for (int j = 0; j < 4; ++j)
                out[(row0 + j) * N_DIM + col] = acc[mi][ni][j] + bvs;
        }
    }
#undef MFMA_QUAD
#undef LOAD_A
#undef LOAD_B
}

// ============================================================================
// Proven round-1 128x128 kernel — runtime fallback if 128KiB dynamic LDS
// cannot be enabled.
// ============================================================================
__global__ __launch_bounds__(256) void gemm_bf16_mfma(
        const unsigned short* __restrict__ xb,
        const unsigned short* __restrict__ wb,
        const float* __restrict__ bias,
        float* __restrict__ out) {
    __shared__ unsigned short sA[128 * 64];
    __shared__ unsigned short sB[128 * 64];

    const int nwg = (M_DIM / 128) * (N_DIM / 128);
    const int q = nwg / 8;
    int bid = blockIdx.x;
    int bid2 = (bid & 7) * q + (bid >> 3);
    const int tm = bid2 & 63;
    const int tn = bid2 >> 6;
    const int r0 = tm * 128;
    const int c0 = tn * 128;

    const int tid  = threadIdx.x;
    const int lane = tid & 63;
    const int wave = tid >> 6;
    const int wr = wave >> 1;
    const int wc = wave & 1;
    const int lr = lane & 15;
    const int t  = lane >> 4;

    int aoff[2][4], boff[2][4];
#pragma unroll
    for (int m = 0; m < 4; ++m) {
        int rowA = wr * 64 + m * 16 + lr;
        int swA  = (rowA & 7) << 4;
        int rowB = wc * 64 + m * 16 + lr;
        int swB  = (rowB & 7) << 4;
#pragma unroll
        for (int kk = 0; kk < 2; ++kk) {
            int cb = kk * 64 + t * 16;
            aoff[kk][m] = rowA * 64 + ((cb ^ swA) >> 1);
            boff[kk][m] = rowB * 64 + ((cb ^ swB) >> 1);
        }
    }

    const int sRow   = lane >> 3;
    const int sChunk = (lane & 7) ^ sRow;
    int aSrc[4], bSrc[4];
    char* ldsA[4];
    char* ldsB[4];
#pragma unroll
    for (int r = 0; r < 4; ++r) {
        int row = r * 32 + wave * 8 + sRow;
        aSrc[r] = (r0 + row) * K_DIM + sChunk * 8;
        bSrc[r] = (c0 + row) * K_DIM + sChunk * 8;
        ldsA[r] = (char*)sA + (r * 4 + wave) * 1024;
        ldsB[r] = (char*)sB + (r * 4 + wave) * 1024;
    }

    f32x4 acc[4][4];
#pragma unroll
    for (int m = 0; m < 4; ++m)
#pragma unroll
        for (int n = 0; n < 4; ++n)
            acc[m][n] = (f32x4){0.f, 0.f, 0.f, 0.f};

    for (int kt = 0; kt < K_DIM / 64; ++kt) {
        const int ko = kt * 64;
#pragma unroll
        for (int r = 0; r < 4; ++r) {
            gload16(xb + aSrc[r] + ko, ldsA[r]);
            gload16(wb + bSrc[r] + ko, ldsB[r]);
        }
        __syncthreads();
#pragma unroll
        for (int kk = 0; kk < 2; ++kk) {
            bf16x8 av[4], bv[4];
#pragma unroll
            for (int m = 0; m < 4; ++m)
                av[m] = *reinterpret_cast<const bf16x8*>(sA + aoff[kk][m]);
#pragma unroll
            for (int n = 0; n < 4; ++n)
                bv[n] = *reinterpret_cast<const bf16x8*>(sB + boff[kk][n]);
#pragma unroll
            for (int m = 0; m < 4; ++m)
#pragma unroll
                for (int n = 0; n < 4; ++n)
                    acc[m][n] = __builtin_amdgcn_mfma_f32_16x16x32_bf16(
                        av[m], bv[n], acc[m][n], 0, 0, 0);
        }
        __syncthreads();
    }

#pragma unroll
    for (int n = 0; n < 4; ++n) {
        const int col = c0 + wc * 64 + n * 16 + lr;
        const float bv = bias[col];
#pragma unroll
        for (int m = 0; m < 4; ++m) {
            const int row0 = r0 + wr * 64 + m * 16 + t * 4;
#pragma unroll
            for (int j = 0; j < 4; ++j)
                out[(row0 + j) * N_DIM + col] = acc[m][n][j] + bv;
        }
    }
}

// ---------- fp32 fallback (only if ws too small) ----------
__global__ void fallback_gemm_f32(const float* __restrict__ x,
                                  const float* __restrict__ w,
                                  const float* __restrict__ bias,
                                  float* __restrict__ out) {
    __shared__ float sX[2][4096];
    const int tid = threadIdx.x;
    const int col = blockIdx.x * 256 + tid;
    const int row0 = blockIdx.y * 2;
    for (int i = tid * 4; i < 8192; i += 1024) {
        int r = i >> 12, c = i & 4095;
        *(float4*)&sX[r][c] = *(const float4*)&x[(size_t)(row0 + r) * 4096 + c];
    }
    __syncthreads();
    const float4* wrow = (const float4*)&w[(size_t)col * 4096];
    float a0 = 0.f, a1 = 0.f;
    for (int k4 = 0; k4 < 1024; ++k4) {
        float4 wv = wrow[k4];
        int k = k4 << 2;
        a0 += wv.x * sX[0][k] + wv.y * sX[0][k + 1] + wv.z * sX[0][k + 2] + wv.w * sX[0][k + 3];
        a1 += wv.x * sX[1][k] + wv.y * sX[1][k + 1] + wv.z * sX[1][k + 2] + wv.w * sX[1][k + 3];
    }
    float bv = bias[col];
    out[(size_t)row0 * 4096 + col] = a0 + bv;
    out[(size_t)(row0 + 1) * 4096 + col] = a1 + bv;
}

extern "C" void kernel_launch(void* const* d_in, const int* in_sizes, int n_in,
                              void* d_out, int out_size, void* d_ws, size_t ws_size,
                              hipStream_t stream) {
    const float* x    = (const float*)d_in[0];
    const float* w    = (const float*)d_in[1];
    const float* bias = (const float*)d_in[2];
    float* out = (float*)d_out;

    const size_t nX = (size_t)M_DIM * K_DIM;
    const size_t nW = (size_t)N_DIM * K_DIM;
    const size_t need = (nX + nW) * sizeof(unsigned short);

    if (ws_size >= need) {
        unsigned short* xb = (unsigned short*)d_ws;
        unsigned short* wb = xb + nX;
        cvt_f32_to_bf16<<<2048, 256, 0, stream>>>(x, xb, (int)(nX / 4));
        cvt_f32_to_bf16<<<1024, 256, 0, stream>>>(w, wb, (int)(nW / 4));
        hipError_t e = hipFuncSetAttribute(
            (const void*)gemm_bf16_256_8ph,
            hipFuncAttributeMaxDynamicSharedMemorySize, 131072);
        if (e == hipSuccess) {
            gemm_bf16_256_8ph<<<(M_DIM / 256) * (N_DIM / 256), 512, 131072, stream>>>(
                xb, wb, bias, out);
        } else {
            gemm_bf16_mfma<<<(M_DIM / 128) * (N_DIM / 128), 256, 0, stream>>>(
                xb, wb, bias, out);
        }
    } else {
        fallback_gemm_f32<<<dim3(N_DIM / 256, M_DIM / 2), 256, 0, stream>>>(x, w, bias, out);
    }
}

// Round 4
// 266.163 us; speedup vs baseline: 1.4762x; 1.0091x over previous
//
#include <hip/hip_runtime.h>
#include <hip/hip_bf16.h>

#define M_DIM 8192
#define N_DIM 4096
#define K_DIM 4096

using bf16x8 = __attribute__((ext_vector_type(8))) short;
using f32x4  = __attribute__((ext_vector_type(4))) float;

// ---------- fp32 -> bf16 (RNE via bit math) ----------
__device__ __forceinline__ unsigned short f2bf(float f) {
    unsigned int u = __float_as_uint(f);
    unsigned int r = u + 0x7fffu + ((u >> 16) & 1u);
    return (unsigned short)(r >> 16);
}

// Single fused conversion: x (n4x float4s) then w (n4w float4s) into ws
// (xb contiguous, wb right after). One launch instead of two.
__global__ void cvt_both_f32_to_bf16(const float* __restrict__ x,
                                     const float* __restrict__ w,
                                     unsigned short* __restrict__ ws,
                                     int n4x, int n4w) {
    int i = blockIdx.x * blockDim.x + threadIdx.x;
    const int stride = gridDim.x * blockDim.x;
    const int total = n4x + n4w;
    uint2* dx = reinterpret_cast<uint2*>(ws);
    uint2* dw = reinterpret_cast<uint2*>(ws) + n4x;
    for (; i < total; i += stride) {
        const bool isX = i < n4x;
        const float4* s4 = isX ? reinterpret_cast<const float4*>(x)
                               : reinterpret_cast<const float4*>(w);
        const int j = isX ? i : i - n4x;
        float4 v = s4[j];
        uint2 o;
        o.x = (unsigned)f2bf(v.x) | ((unsigned)f2bf(v.y) << 16);
        o.y = (unsigned)f2bf(v.z) | ((unsigned)f2bf(v.w) << 16);
        (isX ? dx : dw)[j] = o;
    }
}

// ---------- async global->LDS, 16B per lane ----------
__device__ __forceinline__ void gload16(const unsigned short* g, char* l) {
    __builtin_amdgcn_global_load_lds(
        (const __attribute__((address_space(1))) void*)g,
        (__attribute__((address_space(3))) void*)l, 16, 0, 0);
}

// ============================================================================
// 256x256 8-phase bf16 MFMA GEMM (T1+T2+T3+T4+T5).
// 8 waves (2M x 4N), BK=64, dbuf 128KiB LDS. Structure identical to round 3
// (proven ledger); only the block->tile map changed (L2-locality chunks).
//
// vmcnt ledger (per wave), steady state:
//   enter tile t: outstanding = [B-p1(t)x2, A-q1(t)x2]
//   ph1 +B-p0(t+1) -> 6, wait 4 -> B-p1(t) landed  (read in ph2)
//   ph2 +A-q0(t+1) -> 6, wait 4 -> A-q1(t) landed  (read in ph3)
//   ph3 +B-p1(t+1) -> 6, no wait
//   ph4 +A-q1(t+1) -> 8, wait 4 -> B-p0(t+1), A-q0(t+1) landed (read next ph1)
// Last tile stages ktNext=0 (dummy) so the ledger stays exact; drained after.
//
// Block map (L2 locality): 32x16 tile grid split into 8 chunks of 8tm x 8tn;
// xcd = bid&7 -> chunk (xcd>>1, xcd&1); within chunk c=bid>>3 orders blocks
// as im=c&7, in=c>>3 so the first-dispatched 32 blocks per XCD (co-resident,
// 1 block/CU) form an 8tm x 4tn group: per-K-step footprint 384 KB << 4 MB L2.
// Bijective: tm=(xcd>>1)*8+(c&7), tn=(xcd&1)*8+(c>>3).
// ============================================================================
__global__ __launch_bounds__(512, 2) void gemm_bf16_256_8ph(
        const unsigned short* __restrict__ xb,   // [M,K] bf16 bits
        const unsigned short* __restrict__ wb,   // [N,K] bf16 bits
        const float* __restrict__ bias,          // [N]
        float* __restrict__ out) {               // [M,N]
    extern __shared__ char lds[];
    char* ldsA = lds;           // [2 buf][2 q][16384 B]
    char* ldsB = lds + 65536;   // [2 buf][2 p][16384 B]

    // L2-aware XCD chunk map
    const int bid = blockIdx.x;
    const int xcd = bid & 7;
    const int c   = bid >> 3;                 // 0..63
    const int tm  = (xcd >> 1) * 8 + (c & 7); // 0..31
    const int tn  = (xcd & 1) * 8 + (c >> 3); // 0..15
    const int r0 = tm * 256;
    const int c0 = tn * 256;

    const int tid  = threadIdx.x;
    const int lane = tid & 63;
    const int wave = tid >> 6;        // 0..7
    const int wm = wave >> 2;         // 0..1  (128-row half)
    const int wn = wave & 3;          // 0..3  (64-col strip)
    const int lr = lane & 15;
    const int t4 = lane >> 4;

    // --- ds_read offsets (bytes within one 16KB region), T2-swizzled ---
    int aRd[4][2], bRd[2][2];
    const int swz = (lr & 7) << 4;
#pragma unroll
    for (int ks = 0; ks < 2; ++ks) {
        const int cb = (ks * 64 + t4 * 16) ^ swz;
#pragma unroll
        for (int m = 0; m < 4; ++m)
            aRd[m][ks] = (wm * 64 + m * 16 + lr) * 128 + cb;
#pragma unroll
        for (int n = 0; n < 2; ++n)
            bRd[n][ks] = (wn * 32 + n * 16 + lr) * 128 + cb;
    }

    // --- staging: wave-uniform LDS dest (HW adds lane*16), inverse-swizzled
    //     global source ---
    const int rowInBlk = lane >> 3;                       // 0..7
    const int sChunk   = ((lane & 7) ^ rowInBlk) * 8;     // element offset
    int aSrcB[2], bSrcB[2], dstOff[2];
#pragma unroll
    for (int l = 0; l < 2; ++l) {
        const int R0 = wave * 16 + l * 8;                 // lds row base 0..120
        aSrcB[l] = (r0 + (R0 >> 6) * 128 + (R0 & 63) + rowInBlk) * K_DIM + sChunk;
        bSrcB[l] = (c0 + (R0 >> 5) * 64  + (R0 & 31) + rowInBlk) * K_DIM + sChunk;
        dstOff[l] = R0 * 128;                             // wave-uniform
    }

    auto STAGE_A = [&](int q, int kt, int nb) {
#pragma unroll
        for (int l = 0; l < 2; ++l)
            gload16(xb + aSrcB[l] + q * 64 * K_DIM + kt * 64,
                    ldsA + nb * 32768 + q * 16384 + dstOff[l]);
    };
    auto STAGE_B = [&](int p, int kt, int nb) {
#pragma unroll
        for (int l = 0; l < 2; ++l)
            gload16(wb + bSrcB[l] + p * 32 * K_DIM + kt * 64,
                    ldsB + nb * 32768 + p * 16384 + dstOff[l]);
    };

    f32x4 acc[8][4];
#pragma unroll
    for (int i = 0; i < 8; ++i)
#pragma unroll
        for (int j = 0; j < 4; ++j)
            acc[i][j] = (f32x4){0.f, 0.f, 0.f, 0.f};

    bf16x8 av[4][2], bv0[2][2], bv1[2][2];

#define MFMA_QUAD(M0, N0, BV)                                                  \
    do {                                                                       \
        __builtin_amdgcn_s_setprio(1);                                         \
        _Pragma("unroll") for (int m = 0; m < 4; ++m)                          \
        _Pragma("unroll") for (int n = 0; n < 2; ++n)                          \
        _Pragma("unroll") for (int ks = 0; ks < 2; ++ks)                       \
            acc[(M0) + m][(N0) + n] = __builtin_amdgcn_mfma_f32_16x16x32_bf16( \
                av[m][ks], BV[n][ks], acc[(M0) + m][(N0) + n], 0, 0, 0);       \
        __builtin_amdgcn_s_setprio(0);                                         \
    } while (0)

#define LOAD_A(Q, BUF)                                                         \
    _Pragma("unroll") for (int m = 0; m < 4; ++m)                              \
    _Pragma("unroll") for (int ks = 0; ks < 2; ++ks)                           \
        av[m][ks] = *(const bf16x8*)(ldsA + (BUF) * 32768 + (Q) * 16384 + aRd[m][ks]);

#define LOAD_B(P, BUF, BV)                                                     \
    _Pragma("unroll") for (int n = 0; n < 2; ++n)                              \
    _Pragma("unroll") for (int ks = 0; ks < 2; ++ks)                           \
        BV[n][ks] = *(const bf16x8*)(ldsB + (BUF) * 32768 + (P) * 16384 + bRd[n][ks]);

    // --- prologue: stage tile 0 in steady-state order ---
    STAGE_B(0, 0, 0);
    STAGE_A(0, 0, 0);
    STAGE_B(1, 0, 0);
    STAGE_A(1, 0, 0);
    asm volatile("s_waitcnt vmcnt(4)\n\ts_barrier" ::: "memory");

    const int NT = K_DIM / 64;   // 64
    for (int t = 0; t < NT; ++t) {
        const int buf = t & 1, nbuf = buf ^ 1;
        const int ktNext = (t + 1) & (NT - 1);   // last tile: dummy re-stage of 0
        // ---- ph1: quadrant (0,0); stage B-p0(next) ----
        LOAD_A(0, buf);
        LOAD_B(0, buf, bv0);
        STAGE_B(0, ktNext, nbuf);
        MFMA_QUAD(0, 0, bv0);
        asm volatile("s_waitcnt vmcnt(4)\n\ts_barrier" ::: "memory");
        // ---- ph2: quadrant (0,1); stage A-q0(next) ----
        LOAD_B(1, buf, bv1);
        STAGE_A(0, ktNext, nbuf);
        MFMA_QUAD(0, 2, bv1);
        asm volatile("s_waitcnt vmcnt(4)\n\ts_barrier" ::: "memory");
        // ---- ph3: quadrant (1,1); stage B-p1(next) ----
        LOAD_A(1, buf);
        STAGE_B(1, ktNext, nbuf);
        MFMA_QUAD(4, 2, bv1);
        asm volatile("s_barrier" ::: "memory");
        // ---- ph4: quadrant (1,0); stage A-q1(next) ----
        STAGE_A(1, ktNext, nbuf);
        MFMA_QUAD(4, 0, bv0);
        asm volatile("s_waitcnt vmcnt(4)\n\ts_barrier" ::: "memory");
    }
    asm volatile("s_waitcnt vmcnt(0)" ::: "memory");   // drain dummy stages

    // --- epilogue: C/D layout col=lane&15, row=t4*4+j ---
#pragma unroll
    for (int ni = 0; ni < 4; ++ni) {
        const int col = c0 + wn * 64 + (ni >> 1) * 32 + (ni & 1) * 16 + lr;
        const float bvs = bias[col];
#pragma unroll
        for (int mi = 0; mi < 8; ++mi) {
            const int row0 = r0 + wm * 128 + (mi >> 2) * 64 + (mi & 3) * 16 + t4 * 4;
#pragma unroll
            for (int j = 0; j < 4; ++j)
                out[(row0 + j) * N_DIM + col] = acc[mi][ni][j] + bvs;
        }
    }
#undef MFMA_QUAD
#undef LOAD_A
#undef LOAD_B
}

// ============================================================================
// Proven round-1 128x128 kernel — runtime fallback if 128KiB dynamic LDS
// cannot be enabled.
// ============================================================================
__global__ __launch_bounds__(256) void gemm_bf16_mfma(
        const unsigned short* __restrict__ xb,
        const unsigned short* __restrict__ wb,
        const float* __restrict__ bias,
        float* __restrict__ out) {
    __shared__ unsigned short sA[128 * 64];
    __shared__ unsigned short sB[128 * 64];

    const int nwg = (M_DIM / 128) * (N_DIM / 128);
    const int q = nwg / 8;
    int bid = blockIdx.x;
    int bid2 = (bid & 7) * q + (bid >> 3);
    const int tm = bid2 & 63;
    const int tn = bid2 >> 6;
    const int r0 = tm * 128;
    const int c0 = tn * 128;

    const int tid  = threadIdx.x;
    const int lane = tid & 63;
    const int wave = tid >> 6;
    const int wr = wave >> 1;
    const int wc = wave & 1;
    const int lr = lane & 15;
    const int t  = lane >> 4;

    int aoff[2][4], boff[2][4];
#pragma unroll
    for (int m = 0; m < 4; ++m) {
        int rowA = wr * 64 + m * 16 + lr;
        int swA  = (rowA & 7) << 4;
        int rowB = wc * 64 + m * 16 + lr;
        int swB  = (rowB & 7) << 4;
#pragma unroll
        for (int kk = 0; kk < 2; ++kk) {
            int cb = kk * 64 + t * 16;
            aoff[kk][m] = rowA * 64 + ((cb ^ swA) >> 1);
            boff[kk][m] = rowB * 64 + ((cb ^ swB) >> 1);
        }
    }

    const int sRow   = lane >> 3;
    const int sChunk = (lane & 7) ^ sRow;
    int aSrc[4], bSrc[4];
    char* ldsA[4];
    char* ldsB[4];
#pragma unroll
    for (int r = 0; r < 4; ++r) {
        int row = r * 32 + wave * 8 + sRow;
        aSrc[r] = (r0 + row) * K_DIM + sChunk * 8;
        bSrc[r] = (c0 + row) * K_DIM + sChunk * 8;
        ldsA[r] = (char*)sA + (r * 4 + wave) * 1024;
        ldsB[r] = (char*)sB + (r * 4 + wave) * 1024;
    }

    f32x4 acc[4][4];
#pragma unroll
    for (int m = 0; m < 4; ++m)
#pragma unroll
        for (int n = 0; n < 4; ++n)
            acc[m][n] = (f32x4){0.f, 0.f, 0.f, 0.f};

    for (int kt = 0; kt < K_DIM / 64; ++kt) {
        const int ko = kt * 64;
#pragma unroll
        for (int r = 0; r < 4; ++r) {
            gload16(xb + aSrc[r] + ko, ldsA[r]);
            gload16(wb + bSrc[r] + ko, ldsB[r]);
        }
        __syncthreads();
#pragma unroll
        for (int kk = 0; kk < 2; ++kk) {
            bf16x8 av[4], bv[4];
#pragma unroll
            for (int m = 0; m < 4; ++m)
                av[m] = *reinterpret_cast<const bf16x8*>(sA + aoff[kk][m]);
#pragma unroll
            for (int n = 0; n < 4; ++n)
                bv[n] = *reinterpret_cast<const bf16x8*>(sB + boff[kk][n]);
#pragma unroll
            for (int m = 0; m < 4; ++m)
#pragma unroll
                for (int n = 0; n < 4; ++n)
                    acc[m][n] = __builtin_amdgcn_mfma_f32_16x16x32_bf16(
                        av[m], bv[n], acc[m][n], 0, 0, 0);
        }
        __syncthreads();
    }

#pragma unroll
    for (int n = 0; n < 4; ++n) {
        const int col = c0 + wc * 64 + n * 16 + lr;
        const float bv = bias[col];
#pragma unroll
        for (int m = 0; m < 4; ++m) {
            const int row0 = r0 + wr * 64 + m * 16 + t * 4;
#pragma unroll
            for (int j = 0; j < 4; ++j)
                out[(row0 + j) * N_DIM + col] = acc[m][n][j] + bv;
        }
    }
}

// ---------- fp32 fallback (only if ws too small) ----------
__global__ void fallback_gemm_f32(const float* __restrict__ x,
                                  const float* __restrict__ w,
                                  const float* __restrict__ bias,
                                  float* __restrict__ out) {
    __shared__ float sX[2][4096];
    const int tid = threadIdx.x;
    const int col = blockIdx.x * 256 + tid;
    const int row0 = blockIdx.y * 2;
    for (int i = tid * 4; i < 8192; i += 1024) {
        int r = i >> 12, c = i & 4095;
        *(float4*)&sX[r][c] = *(const float4*)&x[(size_t)(row0 + r) * 4096 + c];
    }
    __syncthreads();
    const float4* wrow = (const float4*)&w[(size_t)col * 4096];
    float a0 = 0.f, a1 = 0.f;
    for (int k4 = 0; k4 < 1024; ++k4) {
        float4 wv = wrow[k4];
        int k = k4 << 2;
        a0 += wv.x * sX[0][k] + wv.y * sX[0][k + 1] + wv.z * sX[0][k + 2] + wv.w * sX[0][k + 3];
        a1 += wv.x * sX[1][k] + wv.y * sX[1][k + 1] + wv.z * sX[1][k + 2] + wv.w * sX[1][k + 3];
    }
    float bv = bias[col];
    out[(size_t)row0 * 4096 + col] = a0 + bv;
    out[(size_t)(row0 + 1) * 4096 + col] = a1 + bv;
}

extern "C" void kernel_launch(void* const* d_in, const int* in_sizes, int n_in,
                              void* d_out, int out_size, void* d_ws, size_t ws_size,
                              hipStream_t stream) {
    const float* x    = (const float*)d_in[0];
    const float* w    = (const float*)d_in[1];
    const float* bias = (const float*)d_in[2];
    float* out = (float*)d_out;

    const size_t nX = (size_t)M_DIM * K_DIM;
    const size_t nW = (size_t)N_DIM * K_DIM;
    const size_t need = (nX + nW) * sizeof(unsigned short);

    if (ws_size >= need) {
        unsigned short* xb = (unsigned short*)d_ws;
        unsigned short* wb = xb + nX;
        cvt_both_f32_to_bf16<<<3072, 256, 0, stream>>>(
            x, w, (unsigned short*)d_ws, (int)(nX / 4), (int)(nW / 4));
        hipError_t e = hipFuncSetAttribute(
            (const void*)gemm_bf16_256_8ph,
            hipFuncAttributeMaxDynamicSharedMemorySize, 131072);
        if (e == hipSuccess) {
            gemm_bf16_256_8ph<<<(M_DIM / 256) * (N_DIM / 256), 512, 131072, stream>>>(
                xb, wb, bias, out);
        } else {
            gemm_bf16_mfma<<<(M_DIM / 128) * (N_DIM / 128), 256, 0, stream>>>(
                xb, wb, bias, out);
        }
    } else {
        fallback_gemm_f32<<<dim3(N_DIM / 256, M_DIM / 2), 256, 0, stream>>>(x, w, bias, out);
    }
}

// Round 5
// 264.256 us; speedup vs baseline: 1.4869x; 1.0072x over previous
//
#include <hip/hip_runtime.h>
#include <hip/hip_bf16.h>

#define M_DIM 8192
#define N_DIM 4096
#define K_DIM 4096

using bf16x8 = __attribute__((ext_vector_type(8))) short;
using f32x4  = __attribute__((ext_vector_type(4))) float;

// ---------- fp32 -> bf16 (RNE via bit math) ----------
__device__ __forceinline__ unsigned short f2bf(float f) {
    unsigned int u = __float_as_uint(f);
    unsigned int r = u + 0x7fffu + ((u >> 16) & 1u);
    return (unsigned short)(r >> 16);
}

// Single fused conversion: x (n4x float4s) then w (n4w float4s) into ws.
__global__ void cvt_both_f32_to_bf16(const float* __restrict__ x,
                                     const float* __restrict__ w,
                                     unsigned short* __restrict__ ws,
                                     int n4x, int n4w) {
    int i = blockIdx.x * blockDim.x + threadIdx.x;
    const int stride = gridDim.x * blockDim.x;
    const int total = n4x + n4w;
    uint2* dx = reinterpret_cast<uint2*>(ws);
    uint2* dw = reinterpret_cast<uint2*>(ws) + n4x;
    for (; i < total; i += stride) {
        const bool isX = i < n4x;
        const float4* s4 = isX ? reinterpret_cast<const float4*>(x)
                               : reinterpret_cast<const float4*>(w);
        const int j = isX ? i : i - n4x;
        float4 v = s4[j];
        uint2 o;
        o.x = (unsigned)f2bf(v.x) | ((unsigned)f2bf(v.y) << 16);
        o.y = (unsigned)f2bf(v.z) | ((unsigned)f2bf(v.w) << 16);
        (isX ? dx : dw)[j] = o;
    }
}

// ---------- async global->LDS, 16B per lane ----------
__device__ __forceinline__ void gload16(const unsigned short* g, char* l) {
    __builtin_amdgcn_global_load_lds(
        (const __attribute__((address_space(1))) void*)g,
        (__attribute__((address_space(3))) void*)l, 16, 0, 0);
}

// ============================================================================
// 256x256 8-phase bf16 MFMA GEMM — round 5: 2-tile-deep prefetch, 1 vmcnt/tile.
//
// Regions (16KB each): A-q in buf parity t&1 holds rows; B-p likewise.
// Region LDS-read lifetimes within tile t: A-q0,B-p0 die end ph1; B-p1 dies
// end ph2; A-q1 dies end ph3. Stages write a region's slot only AFTER its
// death barrier (cross-wave safe: every phase's MFMAs consume that phase's
// ds_reads before the phase barrier, so reads are retired pre-barrier).
//
// Stage schedule (steady state, during tile t):
//   ph1: A-q1(t+1) -> nbuf   (slot died ph3(t-1))
//   ph2: A-q0(t+2) -> buf    (slot died ph1(t))
//   ph3: B-p0(t+2) -> buf    (slot died ph1(t))
//   ph4: B-p1(t+2) -> buf    (slot died ph2(t))
// Single s_waitcnt vmcnt(6) at end of ph4. Coverage (loads issued after the
// region's stage, at the wait preceding its first read; need >= 6):
//   A-q0(tau): staged ph2(tau-2) -> 12 after by end-ph4(tau-1)  OK
//   B-p0(tau): staged ph3(tau-2) -> 10                          OK
//   B-p1(tau): staged ph4(tau-2) ->  8                          OK
//   A-q1(tau): staged ph1(tau-1) ->  6                          OK
// Prologue: t0 x4 (Aq0,Bp0,Bp1,Aq1) + t1 x3 (Aq0,Bp0,Bp1); vmcnt(6) lands all
// of t0 (6 newest = t1's). t1 regions covered by end-ph4(t=0) wait (>=8 after).
// Last tiles stage wrapped kt (dummy) into dead slots; vmcnt(0) after loop.
// ============================================================================
__global__ __launch_bounds__(512, 2) void gemm_bf16_256_8ph(
        const unsigned short* __restrict__ xb,   // [M,K] bf16 bits
        const unsigned short* __restrict__ wb,   // [N,K] bf16 bits
        const float* __restrict__ bias,          // [N]
        float* __restrict__ out) {               // [M,N]
    extern __shared__ char lds[];
    char* ldsA = lds;           // [2 buf][2 q][16384 B]
    char* ldsB = lds + 65536;   // [2 buf][2 p][16384 B]

    // L2-aware XCD chunk map (round 4, kept: FETCH 549->201 MB)
    const int bid = blockIdx.x;
    const int xcd = bid & 7;
    const int c   = bid >> 3;                 // 0..63
    const int tm  = (xcd >> 1) * 8 + (c & 7); // 0..31
    const int tn  = (xcd & 1) * 8 + (c >> 3); // 0..15
    const int r0 = tm * 256;
    const int c0 = tn * 256;

    const int tid  = threadIdx.x;
    const int lane = tid & 63;
    const int wave = tid >> 6;        // 0..7
    const int wm = wave >> 2;         // 0..1  (128-row half)
    const int wn = wave & 3;          // 0..3  (64-col strip)
    const int lr = lane & 15;
    const int t4 = lane >> 4;

    // --- ds_read offsets (bytes within one 16KB region), T2-swizzled ---
    int aRd[4][2], bRd[2][2];
    const int swz = (lr & 7) << 4;
#pragma unroll
    for (int ks = 0; ks < 2; ++ks) {
        const int cb = (ks * 64 + t4 * 16) ^ swz;
#pragma unroll
        for (int m = 0; m < 4; ++m)
            aRd[m][ks] = (wm * 64 + m * 16 + lr) * 128 + cb;
#pragma unroll
        for (int n = 0; n < 2; ++n)
            bRd[n][ks] = (wn * 32 + n * 16 + lr) * 128 + cb;
    }

    // --- staging: wave-uniform LDS dest (HW adds lane*16), inverse-swizzled
    //     global source ---
    const int rowInBlk = lane >> 3;                       // 0..7
    const int sChunk   = ((lane & 7) ^ rowInBlk) * 8;     // element offset
    int aSrcB[2], bSrcB[2], dstOff[2];
#pragma unroll
    for (int l = 0; l < 2; ++l) {
        const int R0 = wave * 16 + l * 8;                 // lds row base 0..120
        aSrcB[l] = (r0 + (R0 >> 6) * 128 + (R0 & 63) + rowInBlk) * K_DIM + sChunk;
        bSrcB[l] = (c0 + (R0 >> 5) * 64  + (R0 & 31) + rowInBlk) * K_DIM + sChunk;
        dstOff[l] = R0 * 128;                             // wave-uniform
    }

    auto STAGE_A = [&](int q, int kt, int nb) {
#pragma unroll
        for (int l = 0; l < 2; ++l)
            gload16(xb + aSrcB[l] + q * 64 * K_DIM + kt * 64,
                    ldsA + nb * 32768 + q * 16384 + dstOff[l]);
    };
    auto STAGE_B = [&](int p, int kt, int nb) {
#pragma unroll
        for (int l = 0; l < 2; ++l)
            gload16(wb + bSrcB[l] + p * 32 * K_DIM + kt * 64,
                    ldsB + nb * 32768 + p * 16384 + dstOff[l]);
    };

    f32x4 acc[8][4];
#pragma unroll
    for (int i = 0; i < 8; ++i)
#pragma unroll
        for (int j = 0; j < 4; ++j)
            acc[i][j] = (f32x4){0.f, 0.f, 0.f, 0.f};

    bf16x8 av[4][2], bv0[2][2], bv1[2][2];

#define MFMA_QUAD(M0, N0, BV)                                                  \
    do {                                                                       \
        __builtin_amdgcn_s_setprio(1);                                         \
        _Pragma("unroll") for (int m = 0; m < 4; ++m)                          \
        _Pragma("unroll") for (int n = 0; n < 2; ++n)                          \
        _Pragma("unroll") for (int ks = 0; ks < 2; ++ks)                       \
            acc[(M0) + m][(N0) + n] = __builtin_amdgcn_mfma_f32_16x16x32_bf16( \
                av[m][ks], BV[n][ks], acc[(M0) + m][(N0) + n], 0, 0, 0);       \
        __builtin_amdgcn_s_setprio(0);                                         \
    } while (0)

#define LOAD_A(Q, BUF)                                                         \
    _Pragma("unroll") for (int m = 0; m < 4; ++m)                              \
    _Pragma("unroll") for (int ks = 0; ks < 2; ++ks)                           \
        av[m][ks] = *(const bf16x8*)(ldsA + (BUF) * 32768 + (Q) * 16384 + aRd[m][ks]);

#define LOAD_B(P, BUF, BV)                                                     \
    _Pragma("unroll") for (int n = 0; n < 2; ++n)                              \
    _Pragma("unroll") for (int ks = 0; ks < 2; ++ks)                           \
        BV[n][ks] = *(const bf16x8*)(ldsB + (BUF) * 32768 + (P) * 16384 + bRd[n][ks]);

    // --- prologue: t0 full (Aq0,Bp0,Bp1,Aq1) + t1 partial (Aq0,Bp0,Bp1) ---
    STAGE_A(0, 0, 0);
    STAGE_B(0, 0, 0);
    STAGE_B(1, 0, 0);
    STAGE_A(1, 0, 0);
    STAGE_A(0, 1, 1);
    STAGE_B(0, 1, 1);
    STAGE_B(1, 1, 1);
    asm volatile("s_waitcnt vmcnt(6)\n\ts_barrier" ::: "memory");

    const int NT = K_DIM / 64;   // 64
    for (int t = 0; t < NT; ++t) {
        const int buf = t & 1, nbuf = buf ^ 1;
        const int kt1 = (t + 1) & (NT - 1);
        const int kt2 = (t + 2) & (NT - 1);
        // ---- ph1: quadrant (0,0); stage A-q1(t+1) -> nbuf ----
        LOAD_A(0, buf);
        LOAD_B(0, buf, bv0);
        STAGE_A(1, kt1, nbuf);
        MFMA_QUAD(0, 0, bv0);
        asm volatile("s_barrier" ::: "memory");
        // ---- ph2: quadrant (0,1); stage A-q0(t+2) -> buf ----
        LOAD_B(1, buf, bv1);
        STAGE_A(0, kt2, buf);
        MFMA_QUAD(0, 2, bv1);
        asm volatile("s_barrier" ::: "memory");
        // ---- ph3: quadrant (1,1); stage B-p0(t+2) -> buf ----
        LOAD_A(1, buf);
        STAGE_B(0, kt2, buf);
        MFMA_QUAD(4, 2, bv1);
        asm volatile("s_barrier" ::: "memory");
        // ---- ph4: quadrant (1,0); stage B-p1(t+2) -> buf; single wait ----
        STAGE_B(1, kt2, buf);
        MFMA_QUAD(4, 0, bv0);
        asm volatile("s_waitcnt vmcnt(6)\n\ts_barrier" ::: "memory");
    }
    asm volatile("s_waitcnt vmcnt(0)" ::: "memory");   // drain dummy stages

    // --- epilogue: C/D layout col=lane&15, row=t4*4+j ---
#pragma unroll
    for (int ni = 0; ni < 4; ++ni) {
        const int col = c0 + wn * 64 + (ni >> 1) * 32 + (ni & 1) * 16 + lr;
        const float bvs = bias[col];
#pragma unroll
        for (int mi = 0; mi < 8; ++mi) {
            const int row0 = r0 + wm * 128 + (mi >> 2) * 64 + (mi & 3) * 16 + t4 * 4;
#pragma unroll
            for (int j = 0; j < 4; ++j)
                out[(row0 + j) * N_DIM + col] = acc[mi][ni][j] + bvs;
        }
    }
#undef MFMA_QUAD
#undef LOAD_A
#undef LOAD_B
}

// ============================================================================
// Proven round-1 128x128 kernel — runtime fallback if 128KiB dynamic LDS
// cannot be enabled.
// ============================================================================
__global__ __launch_bounds__(256) void gemm_bf16_mfma(
        const unsigned short* __restrict__ xb,
        const unsigned short* __restrict__ wb,
        const float* __restrict__ bias,
        float* __restrict__ out) {
    __shared__ unsigned short sA[128 * 64];
    __shared__ unsigned short sB[128 * 64];

    const int nwg = (M_DIM / 128) * (N_DIM / 128);
    const int q = nwg / 8;
    int bid = blockIdx.x;
    int bid2 = (bid & 7) * q + (bid >> 3);
    const int tm = bid2 & 63;
    const int tn = bid2 >> 6;
    const int r0 = tm * 128;
    const int c0 = tn * 128;

    const int tid  = threadIdx.x;
    const int lane = tid & 63;
    const int wave = tid >> 6;
    const int wr = wave >> 1;
    const int wc = wave & 1;
    const int lr = lane & 15;
    const int t  = lane >> 4;

    int aoff[2][4], boff[2][4];
#pragma unroll
    for (int m = 0; m < 4; ++m) {
        int rowA = wr * 64 + m * 16 + lr;
        int swA  = (rowA & 7) << 4;
        int rowB = wc * 64 + m * 16 + lr;
        int swB  = (rowB & 7) << 4;
#pragma unroll
        for (int kk = 0; kk < 2; ++kk) {
            int cb = kk * 64 + t * 16;
            aoff[kk][m] = rowA * 64 + ((cb ^ swA) >> 1);
            boff[kk][m] = rowB * 64 + ((cb ^ swB) >> 1);
        }
    }

    const int sRow   = lane >> 3;
    const int sChunk = (lane & 7) ^ sRow;
    int aSrc[4], bSrc[4];
    char* ldsA[4];
    char* ldsB[4];
#pragma unroll
    for (int r = 0; r < 4; ++r) {
        int row = r * 32 + wave * 8 + sRow;
        aSrc[r] = (r0 + row) * K_DIM + sChunk * 8;
        bSrc[r] = (c0 + row) * K_DIM + sChunk * 8;
        ldsA[r] = (char*)sA + (r * 4 + wave) * 1024;
        ldsB[r] = (char*)sB + (r * 4 + wave) * 1024;
    }

    f32x4 acc[4][4];
#pragma unroll
    for (int m = 0; m < 4; ++m)
#pragma unroll
        for (int n = 0; n < 4; ++n)
            acc[m][n] = (f32x4){0.f, 0.f, 0.f, 0.f};

    for (int kt = 0; kt < K_DIM / 64; ++kt) {
        const int ko = kt * 64;
#pragma unroll
        for (int r = 0; r < 4; ++r) {
            gload16(xb + aSrc[r] + ko, ldsA[r]);
            gload16(wb + bSrc[r] + ko, ldsB[r]);
        }
        __syncthreads();
#pragma unroll
        for (int kk = 0; kk < 2; ++kk) {
            bf16x8 av[4], bv[4];
#pragma unroll
            for (int m = 0; m < 4; ++m)
                av[m] = *reinterpret_cast<const bf16x8*>(sA + aoff[kk][m]);
#pragma unroll
            for (int n = 0; n < 4; ++n)
                bv[n] = *reinterpret_cast<const bf16x8*>(sB + boff[kk][n]);
#pragma unroll
            for (int m = 0; m < 4; ++m)
#pragma unroll
                for (int n = 0; n < 4; ++n)
                    acc[m][n] = __builtin_amdgcn_mfma_f32_16x16x32_bf16(
                        av[m], bv[n], acc[m][n], 0, 0, 0);
        }
        __syncthreads();
    }

#pragma unroll
    for (int n = 0; n < 4; ++n) {
        const int col = c0 + wc * 64 + n * 16 + lr;
        const float bv = bias[col];
#pragma unroll
        for (int m = 0; m < 4; ++m) {
            const int row0 = r0 + wr * 64 + m * 16 + t * 4;
#pragma unroll
            for (int j = 0; j < 4; ++j)
                out[(row0 + j) * N_DIM + col] = acc[m][n][j] + bv;
        }
    }
}

// ---------- fp32 fallback (only if ws too small) ----------
__global__ void fallback_gemm_f32(const float* __restrict__ x,
                                  const float* __restrict__ w,
                                  const float* __restrict__ bias,
                                  float* __restrict__ out) {
    __shared__ float sX[2][4096];
    const int tid = threadIdx.x;
    const int col = blockIdx.x * 256 + tid;
    const int row0 = blockIdx.y * 2;
    for (int i = tid * 4; i < 8192; i += 1024) {
        int r = i >> 12, c = i & 4095;
        *(float4*)&sX[r][c] = *(const float4*)&x[(size_t)(row0 + r) * 4096 + c];
    }
    __syncthreads();
    const float4* wrow = (const float4*)&w[(size_t)col * 4096];
    float a0 = 0.f, a1 = 0.f;
    for (int k4 = 0; k4 < 1024; ++k4) {
        float4 wv = wrow[k4];
        int k = k4 << 2;
        a0 += wv.x * sX[0][k] + wv.y * sX[0][k + 1] + wv.z * sX[0][k + 2] + wv.w * sX[0][k + 3];
        a1 += wv.x * sX[1][k] + wv.y * sX[1][k + 1] + wv.z * sX[1][k + 2] + wv.w * sX[1][k + 3];
    }
    float bv = bias[col];
    out[(size_t)row0 * 4096 + col] = a0 + bv;
    out[(size_t)(row0 + 1) * 4096 + col] = a1 + bv;
}

extern "C" void kernel_launch(void* const* d_in, const int* in_sizes, int n_in,
                              void* d_out, int out_size, void* d_ws, size_t ws_size,
                              hipStream_t stream) {
    const float* x    = (const float*)d_in[0];
    const float* w    = (const float*)d_in[1];
    const float* bias = (const float*)d_in[2];
    float* out = (float*)d_out;

    const size_t nX = (size_t)M_DIM * K_DIM;
    const size_t nW = (size_t)N_DIM * K_DIM;
    const size_t need = (nX + nW) * sizeof(unsigned short);

    if (ws_size >= need) {
        unsigned short* xb = (unsigned short*)d_ws;
        unsigned short* wb = xb + nX;
        cvt_both_f32_to_bf16<<<3072, 256, 0, stream>>>(
            x, w, (unsigned short*)d_ws, (int)(nX / 4), (int)(nW / 4));
        hipError_t e = hipFuncSetAttribute(
            (const void*)gemm_bf16_256_8ph,
            hipFuncAttributeMaxDynamicSharedMemorySize, 131072);
        if (e == hipSuccess) {
            gemm_bf16_256_8ph<<<(M_DIM / 256) * (N_DIM / 256), 512, 131072, stream>>>(
                xb, wb, bias, out);
        } else {
            gemm_bf16_mfma<<<(M_DIM / 128) * (N_DIM / 128), 256, 0, stream>>>(
                xb, wb, bias, out);
        }
    } else {
        fallback_gemm_f32<<<dim3(N_DIM / 256, M_DIM / 2), 256, 0, stream>>>(x, w, bias, out);
    }
}

// Round 6
// 260.831 us; speedup vs baseline: 1.5064x; 1.0131x over previous
//
#include <hip/hip_runtime.h>
#include <hip/hip_bf16.h>

#define M_DIM 8192
#define N_DIM 4096
#define K_DIM 4096

using bf16x8 = __attribute__((ext_vector_type(8))) short;
using f32x4  = __attribute__((ext_vector_type(4))) float;

// ---------- fp32 -> bf16 (RNE via bit math) ----------
__device__ __forceinline__ unsigned short f2bf(float f) {
    unsigned int u = __float_as_uint(f);
    unsigned int r = u + 0x7fffu + ((u >> 16) & 1u);
    return (unsigned short)(r >> 16);
}

// Single fused conversion: x (n4x float4s) then w (n4w float4s) into ws.
__global__ void cvt_both_f32_to_bf16(const float* __restrict__ x,
                                     const float* __restrict__ w,
                                     unsigned short* __restrict__ ws,
                                     int n4x, int n4w) {
    int i = blockIdx.x * blockDim.x + threadIdx.x;
    const int stride = gridDim.x * blockDim.x;
    const int total = n4x + n4w;
    uint2* dx = reinterpret_cast<uint2*>(ws);
    uint2* dw = reinterpret_cast<uint2*>(ws) + n4x;
    for (; i < total; i += stride) {
        const bool isX = i < n4x;
        const float4* s4 = isX ? reinterpret_cast<const float4*>(x)
                               : reinterpret_cast<const float4*>(w);
        const int j = isX ? i : i - n4x;
        float4 v = s4[j];
        uint2 o;
        o.x = (unsigned)f2bf(v.x) | ((unsigned)f2bf(v.y) << 16);
        o.y = (unsigned)f2bf(v.z) | ((unsigned)f2bf(v.w) << 16);
        (isX ? dx : dw)[j] = o;
    }
}

// ---------- async global->LDS, 16B per lane ----------
__device__ __forceinline__ void gload16(const unsigned short* g, char* l) {
    __builtin_amdgcn_global_load_lds(
        (const __attribute__((address_space(1))) void*)g,
        (__attribute__((address_space(3))) void*)l, 16, 0, 0);
}

// ============================================================================
// 256x256 bf16 MFMA GEMM — round 6: cross-barrier ds_read/MFMA decoupling.
// Every phase's MFMA consumes registers loaded in the PREVIOUS phase (across
// a barrier), so the MFMA burst never waits on lgkm and LDS-read serve
// overlaps the MFMA pipe. Read load balanced 4/8/4/8 per tile.
//
// Registers: av[4][2] holds A0 then A1 (overlay: rewritten AFTER its last
// MFMA read in program order); bvA/bvB ping-pong B0(t)/B0(t+1) (2-tile
// unroll); bv1 holds B1(t).
//
// Per tile t (buf = t&1, X = B0(t) regs, Y = B0(t+1) regs):
//  I1: stage A1(t+1)->nbuf ; read bv1<-B1(t)      ; MFMA q00 (av=A0, X); bar
//  I2: stage A0(t+2)->buf  ; MFMA q01 (av=A0,bv1) ; read av<-A1(t); vmcnt(6) bar
//  I3: stage B0(t+2)->buf  ; read Y<-B0(t+1)      ; MFMA q11 (av=A1,bv1); bar
//  I4: stage B1(t+2)->buf  ; MFMA q10 (av=A1, X)  ; read av<-A0(t+1); vmcnt(6) bar
//
// vmcnt coverage (need landed before first read; reads happen after the
// wait's barrier): B1(t) staged I4(t-2): 8 newer at W4(t-1) ✓; A1(t) staged
// I1(t-1): 6 newer at W4(t-1) ✓; B0(t+1) staged I3(t-1): 6 newer at W2(t) ✓;
// A0(t+1) staged I2(t-1): 8 newer at W2(t) ✓.
// Slot deaths: A1 slot dead end-I2(t-1), restaged I1(t) ✓; A0 slot dead
// end-I4(t-1) (reg pre-read), restaged I2(t) ✓; B0 slot dead end-I3(t-1),
// restaged I3(t) ✓; B1 slot dead end-I1(t), restaged I4(t) ✓.
// Prologue: stage t0 x4 + t1 {A0,B0,B1}; vmcnt(6) lands t0; pre-read
// av<-A0(0), bvA<-B0(0). Tail stages wrap (dummy); vmcnt(0) after loop.
// ============================================================================
__global__ __launch_bounds__(512, 2) void gemm_bf16_256_8ph(
        const unsigned short* __restrict__ xb,   // [M,K] bf16 bits
        const unsigned short* __restrict__ wb,   // [N,K] bf16 bits
        const float* __restrict__ bias,          // [N]
        float* __restrict__ out) {               // [M,N]
    extern __shared__ char lds[];
    char* ldsA = lds;           // [2 buf][2 q][16384 B]
    char* ldsB = lds + 65536;   // [2 buf][2 p][16384 B]

    // L2-aware XCD chunk map (round 4: FETCH 549->201 MB)
    const int bid = blockIdx.x;
    const int xcd = bid & 7;
    const int c   = bid >> 3;                 // 0..63
    const int tm  = (xcd >> 1) * 8 + (c & 7); // 0..31
    const int tn  = (xcd & 1) * 8 + (c >> 3); // 0..15
    const int r0 = tm * 256;
    const int c0 = tn * 256;

    const int tid  = threadIdx.x;
    const int lane = tid & 63;
    const int wave = tid >> 6;        // 0..7
    const int wm = wave >> 2;         // 0..1  (128-row half)
    const int wn = wave & 3;          // 0..3  (64-col strip)
    const int lr = lane & 15;
    const int t4 = lane >> 4;

    // --- ds_read offsets (bytes within one 16KB region), T2-swizzled ---
    int aRd[4][2], bRd[2][2];
    const int swz = (lr & 7) << 4;
#pragma unroll
    for (int ks = 0; ks < 2; ++ks) {
        const int cb = (ks * 64 + t4 * 16) ^ swz;
#pragma unroll
        for (int m = 0; m < 4; ++m)
            aRd[m][ks] = (wm * 64 + m * 16 + lr) * 128 + cb;
#pragma unroll
        for (int n = 0; n < 2; ++n)
            bRd[n][ks] = (wn * 32 + n * 16 + lr) * 128 + cb;
    }

    // --- staging: wave-uniform LDS dest (HW adds lane*16), inverse-swizzled
    //     global source ---
    const int rowInBlk = lane >> 3;                       // 0..7
    const int sChunk   = ((lane & 7) ^ rowInBlk) * 8;     // element offset
    int aSrcB[2], bSrcB[2], dstOff[2];
#pragma unroll
    for (int l = 0; l < 2; ++l) {
        const int R0 = wave * 16 + l * 8;                 // lds row base 0..120
        aSrcB[l] = (r0 + (R0 >> 6) * 128 + (R0 & 63) + rowInBlk) * K_DIM + sChunk;
        bSrcB[l] = (c0 + (R0 >> 5) * 64  + (R0 & 31) + rowInBlk) * K_DIM + sChunk;
        dstOff[l] = R0 * 128;                             // wave-uniform
    }

    auto STAGE_A = [&](int q, int kt, int nb) {
#pragma unroll
        for (int l = 0; l < 2; ++l)
            gload16(xb + aSrcB[l] + q * 64 * K_DIM + kt * 64,
                    ldsA + nb * 32768 + q * 16384 + dstOff[l]);
    };
    auto STAGE_B = [&](int p, int kt, int nb) {
#pragma unroll
        for (int l = 0; l < 2; ++l)
            gload16(wb + bSrcB[l] + p * 32 * K_DIM + kt * 64,
                    ldsB + nb * 32768 + p * 16384 + dstOff[l]);
    };

    f32x4 acc[8][4];
#pragma unroll
    for (int i = 0; i < 8; ++i)
#pragma unroll
        for (int j = 0; j < 4; ++j)
            acc[i][j] = (f32x4){0.f, 0.f, 0.f, 0.f};

    bf16x8 av[4][2], bvA[2][2], bvB[2][2], bv1[2][2];

#define MFMA_QUAD(M0, N0, BV)                                                  \
    do {                                                                       \
        __builtin_amdgcn_s_setprio(1);                                         \
        _Pragma("unroll") for (int m = 0; m < 4; ++m)                          \
        _Pragma("unroll") for (int n = 0; n < 2; ++n)                          \
        _Pragma("unroll") for (int ks = 0; ks < 2; ++ks)                       \
            acc[(M0) + m][(N0) + n] = __builtin_amdgcn_mfma_f32_16x16x32_bf16( \
                av[m][ks], BV[n][ks], acc[(M0) + m][(N0) + n], 0, 0, 0);       \
        __builtin_amdgcn_s_setprio(0);                                         \
    } while (0)

#define LOAD_A(Q, BUF)                                                         \
    _Pragma("unroll") for (int m = 0; m < 4; ++m)                              \
    _Pragma("unroll") for (int ks = 0; ks < 2; ++ks)                           \
        av[m][ks] = *(const bf16x8*)(ldsA + (BUF) * 32768 + (Q) * 16384 + aRd[m][ks]);

#define LOAD_B(P, BUF, BV)                                                     \
    _Pragma("unroll") for (int n = 0; n < 2; ++n)                              \
    _Pragma("unroll") for (int ks = 0; ks < 2; ++ks)                           \
        BV[n][ks] = *(const bf16x8*)(ldsB + (BUF) * 32768 + (P) * 16384 + bRd[n][ks]);

    const int NT = K_DIM / 64;   // 64

#define TILE_BODY(T, BUF, XV, YV)                                              \
    do {                                                                       \
        const int nb_  = (BUF) ^ 1;                                           \
        const int kt1_ = ((T) + 1) & (NT - 1);                                 \
        const int kt2_ = ((T) + 2) & (NT - 1);                                 \
        /* I1: MFMA q00 (av=A0, X); read B1(t) */                              \
        STAGE_A(1, kt1_, nb_);                                                 \
        LOAD_B(1, (BUF), bv1);                                                 \
        MFMA_QUAD(0, 0, XV);                                                   \
        asm volatile("s_barrier" ::: "memory");                                \
        /* I2: MFMA q01 (av=A0, bv1); then overlay-read av<-A1(t) */           \
        STAGE_A(0, kt2_, (BUF));                                               \
        MFMA_QUAD(0, 2, bv1);                                                  \
        LOAD_A(1, (BUF));                                                      \
        asm volatile("s_waitcnt vmcnt(6)\n\ts_barrier" ::: "memory");          \
        /* I3: MFMA q11 (av=A1, bv1); read Y<-B0(t+1) */                       \
        STAGE_B(0, kt2_, (BUF));                                               \
        LOAD_B(0, nb_, YV);                                                    \
        MFMA_QUAD(4, 2, bv1);                                                  \
        asm volatile("s_barrier" ::: "memory");                                \
        /* I4: MFMA q10 (av=A1, X); then overlay-read av<-A0(t+1) */           \
        STAGE_B(1, kt2_, (BUF));                                               \
        MFMA_QUAD(4, 0, XV);                                                   \
        LOAD_A(0, nb_);                                                        \
        asm volatile("s_waitcnt vmcnt(6)\n\ts_barrier" ::: "memory");          \
    } while (0)

    // --- prologue: t0 full + t1 {A0,B0,B1}; land t0; pre-read A0(0), B0(0) ---
    STAGE_A(0, 0, 0);
    STAGE_B(0, 0, 0);
    STAGE_B(1, 0, 0);
    STAGE_A(1, 0, 0);
    STAGE_A(0, 1, 1);
    STAGE_B(0, 1, 1);
    STAGE_B(1, 1, 1);
    asm volatile("s_waitcnt vmcnt(6)\n\ts_barrier" ::: "memory");
    LOAD_A(0, 0);          // av  <- A0(0)
    LOAD_B(0, 0, bvA);     // bvA <- B0(0)

    for (int tt = 0; tt < NT / 2; ++tt) {
        TILE_BODY(2 * tt,     0, bvA, bvB);
        TILE_BODY(2 * tt + 1, 1, bvB, bvA);
    }
    asm volatile("s_waitcnt vmcnt(0)" ::: "memory");   // drain dummy stages

    // --- epilogue: C/D layout col=lane&15, row=t4*4+j ---
#pragma unroll
    for (int ni = 0; ni < 4; ++ni) {
        const int col = c0 + wn * 64 + (ni >> 1) * 32 + (ni & 1) * 16 + lr;
        const float bvs = bias[col];
#pragma unroll
        for (int mi = 0; mi < 8; ++mi) {
            const int row0 = r0 + wm * 128 + (mi >> 2) * 64 + (mi & 3) * 16 + t4 * 4;
#pragma unroll
            for (int j = 0; j < 4; ++j)
                out[(row0 + j) * N_DIM + col] = acc[mi][ni][j] + bvs;
        }
    }
#undef TILE_BODY
#undef MFMA_QUAD
#undef LOAD_A
#undef LOAD_B
}

// ============================================================================
// Proven round-1 128x128 kernel — runtime fallback if 128KiB dynamic LDS
// cannot be enabled.
// ============================================================================
__global__ __launch_bounds__(256) void gemm_bf16_mfma(
        const unsigned short* __restrict__ xb,
        const unsigned short* __restrict__ wb,
        const float* __restrict__ bias,
        float* __restrict__ out) {
    __shared__ unsigned short sA[128 * 64];
    __shared__ unsigned short sB[128 * 64];

    const int nwg = (M_DIM / 128) * (N_DIM / 128);
    const int q = nwg / 8;
    int bid = blockIdx.x;
    int bid2 = (bid & 7) * q + (bid >> 3);
    const int tm = bid2 & 63;
    const int tn = bid2 >> 6;
    const int r0 = tm * 128;
    const int c0 = tn * 128;

    const int tid  = threadIdx.x;
    const int lane = tid & 63;
    const int wave = tid >> 6;
    const int wr = wave >> 1;
    const int wc = wave & 1;
    const int lr = lane & 15;
    const int t  = lane >> 4;

    int aoff[2][4], boff[2][4];
#pragma unroll
    for (int m = 0; m < 4; ++m) {
        int rowA = wr * 64 + m * 16 + lr;
        int swA  = (rowA & 7) << 4;
        int rowB = wc * 64 + m * 16 + lr;
        int swB  = (rowB & 7) << 4;
#pragma unroll
        for (int kk = 0; kk < 2; ++kk) {
            int cb = kk * 64 + t * 16;
            aoff[kk][m] = rowA * 64 + ((cb ^ swA) >> 1);
            boff[kk][m] = rowB * 64 + ((cb ^ swB) >> 1);
        }
    }

    const int sRow   = lane >> 3;
    const int sChunk = (lane & 7) ^ sRow;
    int aSrc[4], bSrc[4];
    char* ldsA[4];
    char* ldsB[4];
#pragma unroll
    for (int r = 0; r < 4; ++r) {
        int row = r * 32 + wave * 8 + sRow;
        aSrc[r] = (r0 + row) * K_DIM + sChunk * 8;
        bSrc[r] = (c0 + row) * K_DIM + sChunk * 8;
        ldsA[r] = (char*)sA + (r * 4 + wave) * 1024;
        ldsB[r] = (char*)sB + (r * 4 + wave) * 1024;
    }

    f32x4 acc[4][4];
#pragma unroll
    for (int m = 0; m < 4; ++m)
#pragma unroll
        for (int n = 0; n < 4; ++n)
            acc[m][n] = (f32x4){0.f, 0.f, 0.f, 0.f};

    for (int kt = 0; kt < K_DIM / 64; ++kt) {
        const int ko = kt * 64;
#pragma unroll
        for (int r = 0; r < 4; ++r) {
            gload16(xb + aSrc[r] + ko, ldsA[r]);
            gload16(wb + bSrc[r] + ko, ldsB[r]);
        }
        __syncthreads();
#pragma unroll
        for (int kk = 0; kk < 2; ++kk) {
            bf16x8 av[4], bv[4];
#pragma unroll
            for (int m = 0; m < 4; ++m)
                av[m] = *reinterpret_cast<const bf16x8*>(sA + aoff[kk][m]);
#pragma unroll
            for (int n = 0; n < 4; ++n)
                bv[n] = *reinterpret_cast<const bf16x8*>(sB + boff[kk][n]);
#pragma unroll
            for (int m = 0; m < 4; ++m)
#pragma unroll
                for (int n = 0; n < 4; ++n)
                    acc[m][n] = __builtin_amdgcn_mfma_f32_16x16x32_bf16(
                        av[m], bv[n], acc[m][n], 0, 0, 0);
        }
        __syncthreads();
    }

#pragma unroll
    for (int n = 0; n < 4; ++n) {
        const int col = c0 + wc * 64 + n * 16 + lr;
        const float bv = bias[col];
#pragma unroll
        for (int m = 0; m < 4; ++m) {
            const int row0 = r0 + wr * 64 + m * 16 + t * 4;
#pragma unroll
            for (int j = 0; j < 4; ++j)
                out[(row0 + j) * N_DIM + col] = acc[m][n][j] + bv;
        }
    }
}

// ---------- fp32 fallback (only if ws too small) ----------
__global__ void fallback_gemm_f32(const float* __restrict__ x,
                                  const float* __restrict__ w,
                                  const float* __restrict__ bias,
                                  float* __restrict__ out) {
    __shared__ float sX[2][4096];
    const int tid = threadIdx.x;
    const int col = blockIdx.x * 256 + tid;
    const int row0 = blockIdx.y * 2;
    for (int i = tid * 4; i < 8192; i += 1024) {
        int r = i >> 12, c = i & 4095;
        *(float4*)&sX[r][c] = *(const float4*)&x[(size_t)(row0 + r) * 4096 + c];
    }
    __syncthreads();
    const float4* wrow = (const float4*)&w[(size_t)col * 4096];
    float a0 = 0.f, a1 = 0.f;
    for (int k4 = 0; k4 < 1024; ++k4) {
        float4 wv = wrow[k4];
        int k = k4 << 2;
        a0 += wv.x * sX[0][k] + wv.y * sX[0][k + 1] + wv.z * sX[0][k + 2] + wv.w * sX[0][k + 3];
        a1 += wv.x * sX[1][k] + wv.y * sX[1][k + 1] + wv.z * sX[1][k + 2] + wv.w * sX[1][k + 3];
    }
    float bv = bias[col];
    out[(size_t)row0 * 4096 + col] = a0 + bv;
    out[(size_t)(row0 + 1) * 4096 + col] = a1 + bv;
}

extern "C" void kernel_launch(void* const* d_in, const int* in_sizes, int n_in,
                              void* d_out, int out_size, void* d_ws, size_t ws_size,
                              hipStream_t stream) {
    const float* x    = (const float*)d_in[0];
    const float* w    = (const float*)d_in[1];
    const float* bias = (const float*)d_in[2];
    float* out = (float*)d_out;

    const size_t nX = (size_t)M_DIM * K_DIM;
    const size_t nW = (size_t)N_DIM * K_DIM;
    const size_t need = (nX + nW) * sizeof(unsigned short);

    if (ws_size >= need) {
        unsigned short* xb = (unsigned short*)d_ws;
        unsigned short* wb = xb + nX;
        cvt_both_f32_to_bf16<<<3072, 256, 0, stream>>>(
            x, w, (unsigned short*)d_ws, (int)(nX / 4), (int)(nW / 4));
        hipError_t e = hipFuncSetAttribute(
            (const void*)gemm_bf16_256_8ph,
            hipFuncAttributeMaxDynamicSharedMemorySize, 131072);
        if (e == hipSuccess) {
            gemm_bf16_256_8ph<<<(M_DIM / 256) * (N_DIM / 256), 512, 131072, stream>>>(
                xb, wb, bias, out);
        } else {
            gemm_bf16_mfma<<<(M_DIM / 128) * (N_DIM / 128), 256, 0, stream>>>(
                xb, wb, bias, out);
        }
    } else {
        fallback_gemm_f32<<<dim3(N_DIM / 256, M_DIM / 2), 256, 0, stream>>>(x, w, bias, out);
    }
}